// Round 3
// baseline (118.914 us; speedup 1.0000x reference)
//
#include <hip/hip_runtime.h>

// Problem constants (PointPillarsScatter)
#define NB 4
#define NC 64
#define NH 282
#define NW 282
#define NP 12000
#define HWC (NH * NW)          // 79524, divisible by 4
#define QHW (HWC / 4)          // 19881 int4/float4 per channel plane
#define CLAIM_INTS (NB * HWC)  // 318096 ints = 1.27 MB

// Claim map lives in a device global: sidesteps any ws_size-adequacy question.
// Re-initialized every call (harness poisons nothing here; we own init).
__device__ __align__(16) int g_claim[CLAIM_INTS];

// Pass 0: claim = -1 everywhere (vectorized int4 stores).
__global__ void pps_init_kernel() {
    int gid = blockIdx.x * blockDim.x + threadIdx.x;
    if (gid < CLAIM_INTS / 4) {
        ((int4*)g_claim)[gid] = make_int4(-1, -1, -1, -1);
    }
}

// Pass 1: each valid point claims its cell with atomicMax(point index).
// Last-write-wins (XLA:CPU sequential scatter-set) == highest p wins.
//
// Grid index arithmetic must bit-match the XLA:CPU golden. XLA rewrites
// divide-by-constant into multiply-by-reciprocal; round(1/0.16f) == 6.25f
// exactly. So golden is floorf((x + 22.0f) * 6.25f) in f32 — NOT IEEE
// division (tried r1, ~2 boundary flips) and NOT f64 (tried r2, ~2 flips).
// Diagnostic: if this fails with absmax == 2.5625 again, the harness
// compiles with fast-math (mul == r1's effective code) -> switch to a
// laundered IEEE f32 division next.
__global__ void pps_claim_kernel(const float* __restrict__ pfn_in) {
    int gid = blockIdx.x * blockDim.x + threadIdx.x;
    if (gid >= NB * NP) return;
    int b = gid / NP;
    int p = gid - b * NP;
    const float* base = pfn_in + (size_t)b * 2 * NP;  // [b][2][P][1]
    float x = base[p];
    if (x == 0.0f) return;                      // invalid -> OOB in ref -> dropped
    float y = base[NP + p];
    float tx = (x + 22.0f) * 6.25f;             // == XLA's (x - (-22))/0.16 rewrite
    float ty = (y + 22.0f) * 6.25f;
    int xg = (int)floorf(tx);
    int yg = (int)floorf(ty);
    xg = min(max(xg, 0), NW - 1);
    yg = min(max(yg, 0), NH - 1);
    atomicMax(&g_claim[b * HWC + yg * NW + xg], p);
}

// Pass 2: gather-style fill. One thread per float4 of the output canvas.
// Coalesced float4 writes (also clears the poison); random 4B gathers of
// PFN_output stay L2-resident (3 MB/batch); claim re-reads are L2 hits.
__global__ void pps_fill_kernel(const float* __restrict__ pfn_out,
                                float4* __restrict__ out) {
    int gid = blockIdx.x * blockDim.x + threadIdx.x;
    if (gid >= NB * NC * QHW) return;
    int plane = gid / QHW;               // b*NC + c
    int q = gid - plane * QHW;
    int b = plane >> 6;                  // / NC (NC == 64)
    const int4 cl = ((const int4*)(g_claim + (size_t)b * HWC))[q];
    const float* row = pfn_out + (size_t)plane * NP;   // PFN_output[b][c][:]
    float4 v;
    v.x = (cl.x >= 0) ? row[cl.x] : 0.0f;
    v.y = (cl.y >= 0) ? row[cl.y] : 0.0f;
    v.z = (cl.z >= 0) ? row[cl.z] : 0.0f;
    v.w = (cl.w >= 0) ? row[cl.w] : 0.0f;
    out[gid] = v;
}

extern "C" void kernel_launch(void* const* d_in, const int* in_sizes, int n_in,
                              void* d_out, int out_size, void* d_ws, size_t ws_size,
                              hipStream_t stream) {
    const float* pfn_in  = (const float*)d_in[0];   // (4, 2, 12000, 1) f32
    const float* pfn_out = (const float*)d_in[1];   // (4, 64, 12000)   f32
    float* out = (float*)d_out;                     // (4, 64, 282, 282) f32
    (void)d_ws; (void)ws_size;

    {
        int total = CLAIM_INTS / 4;      // 79524 int4 stores
        int threads = 256;
        pps_init_kernel<<<(total + threads - 1) / threads, threads, 0, stream>>>();
    }
    {
        int total = NB * NP;             // 48000 points
        int threads = 256;
        pps_claim_kernel<<<(total + threads - 1) / threads, threads, 0, stream>>>(pfn_in);
    }
    {
        int total = NB * NC * QHW;       // 5,089,536 float4s
        int threads = 256;
        pps_fill_kernel<<<(total + threads - 1) / threads, threads, 0, stream>>>(pfn_out, (float4*)out);
    }
}